// Round 22
// baseline (167.922 us; speedup 1.0000x reference)
//
#include <hip/hip_runtime.h>

typedef _Float16 f16;
typedef _Float16 f16x2 __attribute__((ext_vector_type(2)));
typedef _Float16 f16x4 __attribute__((ext_vector_type(4)));
typedef _Float16 f16x8 __attribute__((ext_vector_type(8)));
typedef float f32x4 __attribute__((ext_vector_type(4)));

// ---- f16 weight arena in d_ws (units: halfs) ----
// [0, 77824): LDS image (ALL matmul weights), kappa-permuted + XOR-swizzled.
#define L_W1   0             // s1_w *30/2pi   [128][64]
#define L_W2   8192          // s2_w *30/2pi   [256][128]
#define L_WF1  40960         // fc1_w          [64][256]
#define L_WF2  57344         // fc2_w          [64][64]
#define L_WF3  61440         // fc3_w          [256][64]
#define LIMG   77824         // LDS image halfs (155648 B)
#define OFF_WGE 77824        // [16][288] kappa-permuted: rows 0-6 gate, 8-14 experts (L2)
#define OFF_WP2 82432        // p2_w *30/2pi  [32][32] kappa-permuted (L2)
#define TOTH    83456
// ---- fp32 arena at (float*)(ws + TOTH) ----
#define FB_B1  0
#define FB_B2  128
#define FB_F1  384
#define FB_F2  448
#define FB_F3  512
#define FB_GE  768           // gate_b(0..6), 0, exp_b(8..14), 0
#define FB_P2  784
#define FB_PEW 816           // pe_w * 1/2pi   [32][4]
#define FB_PEB 944           // pe_b * 1/2pi   [32]
#define FB_P1W 976           // p1_w * 30/2pi  [32][4]
#define FB_P1B 1104          // p1_b * 30/2pi  [32]
#define FBTOT  1136

#define SIREN_SCL 4.77464829275686f   // 30/(2*pi)
#define INV2PI    0.15915494309189535f

__device__ __forceinline__ float sin_pre(float v){   // v in revolutions
  return __builtin_amdgcn_sinf(__builtin_amdgcn_fractf(v));
}
__device__ __forceinline__ int permk(int k){
  return 16 * ((k & 7) >> 2) + ((k >> 3) & 3) * 4 + (k & 3);
}

// ---------- weight conversion (identical to R19) ----------
__global__ void convert_w(const float* __restrict__ s1w, const float* __restrict__ s1b,
                          const float* __restrict__ s2w, const float* __restrict__ s2b,
                          const float* __restrict__ f1w, const float* __restrict__ f1b,
                          const float* __restrict__ f2w, const float* __restrict__ f2b,
                          const float* __restrict__ f3w, const float* __restrict__ f3b,
                          const float* __restrict__ gw,  const float* __restrict__ gb,
                          const float* __restrict__ ew,  const float* __restrict__ eb,
                          const float* __restrict__ p2w, const float* __restrict__ p2b,
                          const float* __restrict__ pew, const float* __restrict__ peb,
                          const float* __restrict__ p1w, const float* __restrict__ p1b,
                          f16* __restrict__ ws)
{
  int stride = gridDim.x * blockDim.x;
  int t0 = blockIdx.x * blockDim.x + threadIdx.x;
  for (int i = t0; i < TOTH; i += stride){
    float v;
    if (i < L_W2){
      int r = i >> 6, s = i & 63, k = s ^ ((r & 7) << 3);
      v = SIREN_SCL * s1w[(r << 6) + (k & 32) + permk(k & 31)];
    } else if (i < L_WF1){
      int j = i - L_W2, r = j >> 7, s = j & 127, k = s ^ ((r & 7) << 3);
      v = SIREN_SCL * s2w[(r << 7) + (k & 96) + permk(k & 31)];
    } else if (i < L_WF2){
      int j = i - L_WF1, r = j >> 8, s = j & 255, k = s ^ ((r & 7) << 3);
      v = f1w[(r << 8) + (k & 224) + permk(k & 31)];
    } else if (i < L_WF3){
      int j = i - L_WF2, r = j >> 6, s = j & 63, k = s ^ ((r & 7) << 3);
      v = f2w[(r << 6) + (k & 32) + permk(k & 31)];
    } else if (i < OFF_WGE){
      int j = i - L_WF3, r = j >> 6, s = j & 63, k = s ^ ((r & 7) << 3);
      v = f3w[(r << 6) + (k & 32) + permk(k & 31)];
    } else if (i < OFF_WP2){
      int j = i - OFF_WGE, r = j / 288, k = j - r * 288;
      int p = (k & ~31) + permk(k & 31);
      v = (r < 7) ? gw[r * 288 + p]
        : ((r >= 8 && r < 15 && p < 256) ? ew[(r - 8) * 256 + p] : 0.f);
    } else {
      int j = i - OFF_WP2, r = j >> 5, k = j & 31;
      v = SIREN_SCL * p2w[(r << 5) + permk(k)];
    }
    ws[i] = (f16)v;
  }
  float* bws = (float*)(ws + TOTH);
  for (int i = t0; i < FBTOT; i += stride){
    float v;
    if (i < 128)      v = SIREN_SCL * s1b[i];
    else if (i < 384) v = SIREN_SCL * s2b[i - 128];
    else if (i < 448) v = f1b[i - 384];
    else if (i < 512) v = f2b[i - 448];
    else if (i < 768) v = f3b[i - 512];
    else if (i < 784){ int j = i - 768;
      v = (j < 7) ? gb[j] : ((j >= 8 && j < 15) ? eb[j - 8] : 0.0f); }
    else if (i < 816) v = SIREN_SCL * p2b[i - 784];
    else if (i < 944) v = INV2PI * pew[i - FB_PEW];
    else if (i < 976) v = INV2PI * peb[i - FB_PEB];
    else if (i < 1104) v = SIREN_SCL * p1w[i - FB_P1W];
    else v = SIREN_SCL * p1b[i - FB_P1B];
    bws[i] = v;
  }
}

// packed f32->f16x2 conversion (verified exact on this net: R18/R19)
__device__ __forceinline__ f16x4 pk4(float a, float b, float c, float d){
  f16x2 lo = __builtin_bit_cast(f16x2, __builtin_amdgcn_cvt_pkrtz(a, b));
  f16x2 hi = __builtin_bit_cast(f16x2, __builtin_amdgcn_cvt_pkrtz(c, d));
  return __builtin_shufflevector(lo, hi, 0, 1, 2, 3);
}
__device__ __forceinline__ f16x4 sin4p(f32x4 a){
  return pk4(sin_pre(a[0]), sin_pre(a[1]), sin_pre(a[2]), sin_pre(a[3]));
}
__device__ __forceinline__ f16x4 relu4(f32x4 a){
  return pk4(fmaxf(a[0],0.f), fmaxf(a[1],0.f), fmaxf(a[2],0.f), fmaxf(a[3],0.f));
}
__device__ __forceinline__ f16x4 resrelu4(f32x4 a, f16x4 old){
  return pk4(fmaxf(a[0]+(float)old[0],0.f), fmaxf(a[1]+(float)old[1],0.f),
             fmaxf(a[2]+(float)old[2],0.f), fmaxf(a[3]+(float)old[3],0.f));
}
#define SHUF8(A_, B_) __builtin_shufflevector(A_, B_, 0, 1, 2, 3, 4, 5, 6, 7)

// AGPR stash (unified file): h2 lives in 32 AGPRs between s2 and the gate.
__device__ __forceinline__ void ag_w(float& a0, float& a1, f16x4 v){
  float2 f = __builtin_bit_cast(float2, v);
  asm("v_accvgpr_write_b32 %0, %2\n\tv_accvgpr_write_b32 %1, %3"
      : "=a"(a0), "=a"(a1) : "v"(f.x), "v"(f.y));
}
__device__ __forceinline__ f16x4 ag_r(float a0, float a1){
  float2 f;
  asm("v_accvgpr_read_b32 %0, %2\n\tv_accvgpr_read_b32 %1, %3"
      : "=v"(f.x), "=v"(f.y) : "a"(a0), "a"(a1));
  return __builtin_bit_cast(f16x4, f);
}

// 3-waves/SIMD experiment: 768-thr block (12 waves), 16 rows/wave, all weights
// in LDS (152KB -> 1 block/CU), h2 entirely in AGPRs. launch_bounds(768,3)
// implies an ~85 arch-VGPR cap (allocator rule: 256/min_waves); single-group
// live set ~55 fits. Grid 2731, wave-uniform tail guard.
__global__ __launch_bounds__(768, 3) void moe_main(
    const float* __restrict__ x,
    const f16* __restrict__ ws, float* __restrict__ out)
{
  const float* bws = (const float*)(ws + TOTH);
  __shared__ __align__(16) f16 wlds[LIMG];   // 155648 B

  const int tid = threadIdx.x;
  const int lane = tid & 63, wid = tid >> 6;       // wid 0..11
  const int l15 = lane & 15, lk = lane >> 4;
  const int swzh = (l15 & 7) << 3;
  const long long wrow0 = ((long long)blockIdx.x * 12 + wid) * 16;
  const bool valid = wrow0 < 524288;               // wave-uniform tail guard
  const long long grow = wrow0 + l15;

  float ag[32];                                    // AGPR stash (const indices)

  // ---- stage all weights L2 -> LDS (all waves, incl. guarded ones) ----
  for (int i = tid * 8; i < LIMG; i += 6144)
    *(float4*)(wlds + i) = *(const float4*)(ws + i);

  f16x4 h0q[4], f1q[2], f2q[2];
  if (valid){
    // ---- PE + policy-1 (pre-scaled to revolutions) ----
    float4 xv = ((const float4*)x)[grow];
    const float4* pe4 = (const float4*)(bws + FB_PEW);
    const float4* p14 = (const float4*)(bws + FB_P1W);
    #pragma unroll
    for (int c = 0; c < 2; ++c)
      #pragma unroll
      for (int i = 0; i < 4; ++i){
        int d = c * 16 + lk * 4 + i;
        float4 w  = pe4[d]; float wb = bws[FB_PEB + d];
        float4 wp = p14[d]; float pb = bws[FB_P1B + d];
        float u = fmaf(xv.x,w.x,fmaf(xv.y,w.y,fmaf(xv.z,w.z,fmaf(xv.w,w.w,wb))));
        h0q[c][i]     = (f16)sin_pre(u);
        h0q[2 + c][i] = (f16)sin_pre(u + 0.25f);   // cos
        float z = fmaf(xv.x,wp.x,fmaf(xv.y,wp.y,fmaf(xv.z,wp.z,fmaf(xv.w,wp.w,pb))));
        f1q[c][i] = (f16)sin_pre(z);
      }

    // ---- policy-2 (L2 weights, kappa-permuted) ----
    f16x8 bfp = SHUF8(f1q[0], f1q[1]);
    #pragma unroll
    for (int ct = 0; ct < 2; ++ct){
      float4 b4 = *(const float4*)(bws + FB_P2 + ct * 16 + lk * 4);
      f16x8 wv = *(const f16x8*)(ws + OFF_WP2 + (ct * 16 + l15) * 32 + 8 * lk);
      f32x4 acc = {b4.x, b4.y, b4.z, b4.w};
      acc = __builtin_amdgcn_mfma_f32_16x16x32_f16(wv, bfp, acc, 0, 0, 0);
      f2q[ct] = sin4p(acc);
    }
  }

  __syncthreads();   // weights staged (the only barrier)
  if (!valid) return;

  // ---- s1 ----
  f16x4 h1q[8];
  #pragma unroll
  for (int ct = 0; ct < 8; ++ct){
    float4 b4 = *(const float4*)(bws + FB_B1 + ct * 16 + lk * 4);
    f32x4 acc = {b4.x, b4.y, b4.z, b4.w};
    #pragma unroll
    for (int ks = 0; ks < 2; ++ks){
      f16x8 wv = *(const f16x8*)(wlds + L_W1 + (ct*16+l15)*64 + ((32*ks + 8*lk) ^ swzh));
      acc = __builtin_amdgcn_mfma_f32_16x16x32_f16(wv, SHUF8(h0q[2*ks], h0q[2*ks+1]), acc, 0, 0, 0);
    }
    h1q[ct] = sin4p(acc);
  }

  // ---- s2: outputs straight to AGPR stash (32 writes) ----
  #pragma unroll
  for (int ct = 0; ct < 16; ++ct){
    float4 b4 = *(const float4*)(bws + FB_B2 + ct * 16 + lk * 4);
    f32x4 acc = {b4.x, b4.y, b4.z, b4.w};
    #pragma unroll
    for (int ks = 0; ks < 4; ++ks){
      f16x8 wv = *(const f16x8*)(wlds + L_W2 + (ct*16+l15)*128 + ((32*ks + 8*lk) ^ swzh));
      acc = __builtin_amdgcn_mfma_f32_16x16x32_f16(wv, SHUF8(h1q[2*ks], h1q[2*ks+1]), acc, 0, 0, 0);
    }
    ag_w(ag[2*ct], ag[2*ct+1], sin4p(acc));
  }

  // ---- fc1 (ks-outer: each stashed pair read back once) ----
  f16x4 t1q[4];
  {
    f32x4 acc1[4];
    #pragma unroll
    for (int ct = 0; ct < 4; ++ct){
      float4 b4 = *(const float4*)(bws + FB_F1 + ct * 16 + lk * 4);
      acc1[ct] = (f32x4){b4.x, b4.y, b4.z, b4.w};
    }
    #pragma unroll
    for (int ks = 0; ks < 8; ++ks){
      f16x8 bf = SHUF8(ag_r(ag[4*ks], ag[4*ks+1]), ag_r(ag[4*ks+2], ag[4*ks+3]));
      #pragma unroll
      for (int ct = 0; ct < 4; ++ct){
        f16x8 wv = *(const f16x8*)(wlds + L_WF1 + (ct*16+l15)*256 + ((32*ks + 8*lk) ^ swzh));
        acc1[ct] = __builtin_amdgcn_mfma_f32_16x16x32_f16(wv, bf, acc1[ct], 0, 0, 0);
      }
    }
    #pragma unroll
    for (int ct = 0; ct < 4; ++ct) t1q[ct] = relu4(acc1[ct]);
  }

  // ---- fc2 ----
  f16x4 t2q[4];
  #pragma unroll
  for (int ct = 0; ct < 4; ++ct){
    float4 b4 = *(const float4*)(bws + FB_F2 + ct * 16 + lk * 4);
    f32x4 acc = {b4.x, b4.y, b4.z, b4.w};
    #pragma unroll
    for (int ks = 0; ks < 2; ++ks){
      f16x8 wv = *(const f16x8*)(wlds + L_WF2 + (ct*16+l15)*64 + ((32*ks + 8*lk) ^ swzh));
      acc = __builtin_amdgcn_mfma_f32_16x16x32_f16(wv, SHUF8(t1q[2*ks], t1q[2*ks+1]), acc, 0, 0, 0);
    }
    t2q[ct] = relu4(acc);
  }

  // ---- fc3 + residual: read old h2 from stash, write updated h2 back ----
  #pragma unroll
  for (int ct = 0; ct < 16; ++ct){
    float4 b4 = *(const float4*)(bws + FB_F3 + ct * 16 + lk * 4);
    f32x4 acc = {b4.x, b4.y, b4.z, b4.w};
    #pragma unroll
    for (int ks = 0; ks < 2; ++ks){
      f16x8 wv = *(const f16x8*)(wlds + L_WF3 + (ct*16+l15)*64 + ((32*ks + 8*lk) ^ swzh));
      acc = __builtin_amdgcn_mfma_f32_16x16x32_f16(wv, SHUF8(t2q[2*ks], t2q[2*ks+1]), acc, 0, 0, 0);
    }
    f16x4 old = ag_r(ag[2*ct], ag[2*ct+1]);
    ag_w(ag[2*ct], ag[2*ct+1], resrelu4(acc, old));
  }

  // ---- gate + experts (swapped) + in-wave softmax/routing ----
  {
    float4 gb = ((const float4*)(bws + FB_GE))[lk];
    f32x4 acc = {gb.x, gb.y, gb.z, gb.w};
    #pragma unroll
    for (int ks = 0; ks < 8; ++ks){
      f16x8 wv = *(const f16x8*)(ws + OFF_WGE + l15 * 288 + 32 * ks + 8 * lk);
      f16x8 bf = SHUF8(ag_r(ag[4*ks], ag[4*ks+1]), ag_r(ag[4*ks+2], ag[4*ks+3]));
      acc = __builtin_amdgcn_mfma_f32_16x16x32_f16(wv, bf, acc, 0, 0, 0);
    }
    {
      f16x8 wv = *(const f16x8*)(ws + OFF_WGE + l15 * 288 + 256 + 8 * lk);
      acc = __builtin_amdgcn_mfma_f32_16x16x32_f16(wv, SHUF8(f2q[0], f2q[1]), acc, 0, 0, 0);
    }
    // lane (l15,lk): gate rows m=4lk+i for batch row l15; lk<2 logits, lk>=2 preds
    float pred[4], lg[4];
    #pragma unroll
    for (int i = 0; i < 4; ++i) pred[i] = __shfl_xor(acc[i], 32);
    #pragma unroll
    for (int i = 0; i < 4; ++i) lg[i] = acc[i];
    if (lk == 1) lg[3] = -1e30f;               // gate row 7 = padding
    float mx = fmaxf(fmaxf(lg[0], lg[1]), fmaxf(lg[2], lg[3]));
    mx = fmaxf(mx, __shfl_xor(mx, 16));
    float s = 0.f, y = 0.f;
    #pragma unroll
    for (int i = 0; i < 4; ++i){ float p = __expf(lg[i] - mx); s += p; y += p * pred[i]; }
    s += __shfl_xor(s, 16); y += __shfl_xor(y, 16);
    if (lk == 0) out[grow] = y / s;
  }
}

extern "C" void kernel_launch(void* const* d_in, const int* in_sizes, int n_in,
                              void* d_out, int out_size, void* d_ws, size_t ws_size,
                              hipStream_t stream)
{
  const float* x     = (const float*)d_in[0];
  const float* pe_w  = (const float*)d_in[1];
  const float* pe_b  = (const float*)d_in[2];
  const float* s1_w  = (const float*)d_in[3];
  const float* s1_b  = (const float*)d_in[4];
  const float* s2_w  = (const float*)d_in[5];
  const float* s2_b  = (const float*)d_in[6];
  const float* fc1_w = (const float*)d_in[7];
  const float* fc1_b = (const float*)d_in[8];
  const float* fc2_w = (const float*)d_in[9];
  const float* fc2_b = (const float*)d_in[10];
  const float* fc3_w = (const float*)d_in[11];
  const float* fc3_b = (const float*)d_in[12];
  const float* p1_w  = (const float*)d_in[13];
  const float* p1_b  = (const float*)d_in[14];
  const float* p2_w  = (const float*)d_in[15];
  const float* p2_b  = (const float*)d_in[16];
  const float* gate_w= (const float*)d_in[17];
  const float* gate_b= (const float*)d_in[18];
  const float* exp_w = (const float*)d_in[19];
  const float* exp_b = (const float*)d_in[20];
  f16* ws = (f16*)d_ws;

  convert_w<<<128, 256, 0, stream>>>(s1_w, s1_b, s2_w, s2_b, fc1_w, fc1_b, fc2_w, fc2_b,
                                     fc3_w, fc3_b, gate_w, gate_b, exp_w, exp_b, p2_w, p2_b,
                                     pe_w, pe_b, p1_w, p1_b, ws);
  // 2731 blocks x 192 rows = 524352 >= 524288 (tail guarded in-kernel)
  moe_main<<<2731, 768, 0, stream>>>(x, ws, (float*)d_out);
}